// Round 12
// baseline (2503.690 us; speedup 1.0000x reference)
//
#include <hip/hip_runtime.h>
#include <hip/hip_bf16.h>
#include <cstddef>

#define H    50
#define G4   200   // 4*H
#define TT   1024
#define BB   512
#define BLK  512   // 8 waves: 0..3 h-waves (lane=(unit,qK)), 4..7 x-waves (MODE!=0)

__device__ __forceinline__ float sigm(float x) { return 1.0f / (1.0f + __expf(-x)); }
__device__ __forceinline__ float tanh_fast(float x){ return 1.0f - 2.0f / (__expf(2.0f*x) + 1.0f); }

// lgkm-only barrier (global loads/stores stay in flight)
#define BAR() do { asm volatile("s_waitcnt lgkmcnt(0)" ::: "memory"); \
                   __builtin_amdgcn_s_barrier(); } while (0)

// quad butterfly sum via DPP quad_perm (pure VALU) — replaces ds_bpermute shfl_xor
#define QSUM(v) do { \
  int _d = __builtin_amdgcn_mov_dpp(__float_as_int(v), 0xB1, 0xF, 0xF, true); \
  (v) += __int_as_float(_d); \
  _d = __builtin_amdgcn_mov_dpp(__float_as_int(v), 0x4E, 0xF, 0xF, true); \
  (v) += __int_as_float(_d); \
} while (0)

// ---- 13 named scalar weights ----
#define D13(P) float P##0,P##1,P##2,P##3,P##4,P##5,P##6,P##7,P##8,P##9,P##10,P##11,P##12

#define WL13(P, WPTR, ROW, K0) do { const float* _w = (WPTR) + (size_t)(ROW) * H; const int _k = (K0); \
  P##0 =(_k+ 0<H)?_w[_k+ 0]:0.f; P##1 =(_k+ 1<H)?_w[_k+ 1]:0.f; P##2 =(_k+ 2<H)?_w[_k+ 2]:0.f; \
  P##3 =(_k+ 3<H)?_w[_k+ 3]:0.f; P##4 =(_k+ 4<H)?_w[_k+ 4]:0.f; P##5 =(_k+ 5<H)?_w[_k+ 5]:0.f; \
  P##6 =(_k+ 6<H)?_w[_k+ 6]:0.f; P##7 =(_k+ 7<H)?_w[_k+ 7]:0.f; P##8 =(_k+ 8<H)?_w[_k+ 8]:0.f; \
  P##9 =(_k+ 9<H)?_w[_k+ 9]:0.f; P##10=(_k+10<H)?_w[_k+10]:0.f; P##11=(_k+11<H)?_w[_k+11]:0.f; \
  P##12=(_k+12<H)?_w[_k+12]:0.f; } while (0)

// aligned 13-slice read from a [4][16] LDS bank: 3x ds_read_b128 + 1x b32
#define LDSLICE(A4, B4, C4, S1, BASE) do { \
  const float4* _p = (const float4*)(BASE); \
  A4 = _p[0]; B4 = _p[1]; C4 = _p[2]; S1 = ((const float*)(BASE))[12]; } while (0)

#define DOT13Q(W, A4, B4, C4, S1, ACC) do { \
  ACC=__fmaf_rn(W##0, (A4).x,ACC); ACC=__fmaf_rn(W##1, (A4).y,ACC); \
  ACC=__fmaf_rn(W##2, (A4).z,ACC); ACC=__fmaf_rn(W##3, (A4).w,ACC); \
  ACC=__fmaf_rn(W##4, (B4).x,ACC); ACC=__fmaf_rn(W##5, (B4).y,ACC); \
  ACC=__fmaf_rn(W##6, (B4).z,ACC); ACC=__fmaf_rn(W##7, (B4).w,ACC); \
  ACC=__fmaf_rn(W##8, (C4).x,ACC); ACC=__fmaf_rn(W##9, (C4).y,ACC); \
  ACC=__fmaf_rn(W##10,(C4).z,ACC); ACC=__fmaf_rn(W##11,(C4).w,ACC); \
  ACC=__fmaf_rn(W##12,(S1),  ACC); } while (0)

// One time step. CUR is a compile-time 0/1; T runtime.
#define STEP(CUR, T) do { \
  if (hw) { \
    float4 hA,hB,hC; float h12; \
    LDSLICE(hA,hB,hC,h12, &h_s[CUR][qh][0]); \
    float a0=0.f,a1=0.f,a2=0.f,a3=0.f; \
    DOT13Q(wA,hA,hB,hC,h12,a0); DOT13Q(wB,hA,hB,hC,h12,a1); \
    DOT13Q(wC,hA,hB,hC,h12,a2); DOT13Q(wD,hA,hB,hC,h12,a3); \
    if (MODE != 0) { \
      const float4 xw4 = *(const float4*)&xw_s[CUR][uh][qh][0]; \
      a0 += xw4.x; a1 += xw4.y; a2 += xw4.z; a3 += xw4.w; \
    } \
    QSUM(a0); QSUM(a1); QSUM(a2); QSUM(a3); \
    if (MODE == 0) { float _xt = x_s[T]; \
      a0=__fmaf_rn(wi0,_xt,a0); a1=__fmaf_rn(wi1,_xt,a1); \
      a2=__fmaf_rn(wi2,_xt,a2); a3=__fmaf_rn(wi3,_xt,a3); } \
    float iv = sigm(a0 + bb0), fv = sigm(a1 + bb1); \
    float gv = tanh_fast(a2 + bb2), ov = sigm(a3 + bb3); \
    c_r  = __fmaf_rn(fv, c_r, iv * gv); \
    hval = ov * tanh_fast(c_r); \
    if (hvalid) { \
      h_s[(CUR)^1][slcw][idxw] = hval; \
      if (MODE != 2) hout[hob + (size_t)(T) * H + uh] = hval; \
    } \
  } else if (MODE != 0) { \
    if ((T) + 1 < TT) { /* xw partials for step T+1 from xls ring */ \
      float4 xA,xB,xC; float x12; \
      LDSLICE(xA,xB,xC,x12, &xls[((T)+1)&1][qh][0]); \
      float p0=0.f,p1=0.f,p2=0.f,p3=0.f; \
      DOT13Q(wA,xA,xB,xC,x12,p0); DOT13Q(wB,xA,xB,xC,x12,p1); \
      DOT13Q(wC,xA,xB,xC,x12,p2); DOT13Q(wD,xA,xB,xC,x12,p3); \
      *(float4*)&xw_s[(CUR)^1][uh][qh][0] = make_float4(p0,p1,p2,p3); \
    } \
    float r_next = 0.f; \
    if (xio && (T) + 3 < TT) r_next = xrow[(size_t)((T)+3) * H + ln]; /* issue early */ \
    if (xio && (T) + 2 < TT) xls[(T)&1][slcx][idxx] = r_cur;          /* land x_{T+2} */ \
    r_cur = r_next; \
  } \
  BAR(); \
} while (0)

// MODE 0: first layer (scalar x); MODE 1: middle; MODE 2: last + dense head
template <int MODE>
__global__ __launch_bounds__(BLK, 4) __attribute__((amdgpu_waves_per_eu(4, 4)))
void lstm_kernel(
    const float* __restrict__ xin,
    const float* __restrict__ w_ih,    // [G4][H] (MODE0: [G4][1])
    const float* __restrict__ w_hh,    // [G4][H]
    const float* __restrict__ b_ih,    // [G4]
    const float* __restrict__ b_hh,    // [G4]
    float* __restrict__ hout,          // [B][T][H] (MODE 0,1)
    const float* __restrict__ w_dense, // [H]   (MODE 2)
    const float* __restrict__ b_dense, // [1]   (MODE 2)
    float* __restrict__ out)           // [B]   (MODE 2)
{
    const int b   = blockIdx.x;
    const int tid = threadIdx.x;
    const int wv  = tid >> 6;
    const int ln  = tid & 63;
    const bool hw = (wv < 4);                 // h-wave role; waves 4..7 = x-waves

    // (unit, K-quarter) mapping shared by both roles
    const int uh  = (wv & 3) * 16 + (ln >> 2);   // 0..63 (valid < 50)
    const int qh  = ln & 3;
    const int k0h = 13 * qh;
    const int uch = (uh < H) ? uh : (H - 1);
    const bool hvalid = hw && (uh < H) && (qh == 0);
    const int slcw = uch / 13, idxw = uch % 13;   // h writer slot
    const int slcx = (ln < H ? ln : 0) / 13, idxx = (ln < H ? ln : 0) % 13;
    const bool xio = (MODE != 0) && (wv == 4) && (ln < H);  // sole x loader/writer wave

    __shared__ __align__(16) float h_s[2][4][16];        // h in 13-slices (16-padded)
    __shared__ __align__(16) float xw_s[2][64][4][4];    // x-dot partials as float4
    __shared__ __align__(16) float xls[2][4][16];        // x_t ring, slice layout
    __shared__ float x_s[MODE == 0 ? TT : 1];            // MODE0: whole scalar row

    // ---- weights: 4 gate rows x 13-slice = 52 named scalars ----
    D13(wA); D13(wB); D13(wC); D13(wD);
    float wi0=0.f, wi1=0.f, wi2=0.f, wi3=0.f;
    float bb0=0.f, bb1=0.f, bb2=0.f, bb3=0.f;

    const float* __restrict__ xrow = xin + (size_t)b * TT * (MODE == 0 ? 1 : H);
    const size_t hob = (size_t)b * TT * H;

    if (hw) {
        WL13(wA, w_hh, 0 * H + uch, k0h);
        WL13(wB, w_hh, 1 * H + uch, k0h);
        WL13(wC, w_hh, 2 * H + uch, k0h);
        WL13(wD, w_hh, 3 * H + uch, k0h);
        bb0 = b_ih[0 * H + uch] + b_hh[0 * H + uch];
        bb1 = b_ih[1 * H + uch] + b_hh[1 * H + uch];
        bb2 = b_ih[2 * H + uch] + b_hh[2 * H + uch];
        bb3 = b_ih[3 * H + uch] + b_hh[3 * H + uch];
        if (MODE == 0) {
            wi0 = w_ih[0 * H + uch]; wi1 = w_ih[1 * H + uch];
            wi2 = w_ih[2 * H + uch]; wi3 = w_ih[3 * H + uch];
        }
    } else if (MODE != 0) {
        WL13(wA, w_ih, 0 * H + uch, k0h);
        WL13(wB, w_ih, 1 * H + uch, k0h);
        WL13(wC, w_ih, 2 * H + uch, k0h);
        WL13(wD, w_ih, 3 * H + uch, k0h);
    }
    float wdr = 0.f;
    if (MODE == 2 && wv == 0 && ln < H) wdr = w_dense[ln];

    // ---- init LDS ----
    if (tid < 128) (&h_s[0][0][0])[tid] = 0.f;                 // full zero (h0 = 0 + pads)
    if (tid >= 128 && tid < 132) {                             // xls read-but-unwritten pads
        int z = tid - 128; xls[z >> 1][3][11 + (z & 1)] = 0.f;
    }
    if (MODE == 0) {
        for (int i = tid; i < TT; i += BLK) x_s[i] = xrow[i];
    } else if (xio) {
        xls[0][slcx][idxx] = xrow[ln];          // x_0
        xls[1][slcx][idxx] = xrow[H + ln];      // x_1
    }
    __syncthreads();
    if (MODE != 0 && !hw) {                      // xw partials for t=0 from x_0
        float4 xA,xB,xC; float x12;
        LDSLICE(xA,xB,xC,x12, &xls[0][qh][0]);
        float p0=0.f,p1=0.f,p2=0.f,p3=0.f;
        DOT13Q(wA,xA,xB,xC,x12,p0); DOT13Q(wB,xA,xB,xC,x12,p1);
        DOT13Q(wC,xA,xB,xC,x12,p2); DOT13Q(wD,xA,xB,xC,x12,p3);
        *(float4*)&xw_s[0][uh][qh][0] = make_float4(p0,p1,p2,p3);
    }
    float r_cur = 0.f;
    if (xio) r_cur = xrow[(size_t)2 * H + ln];   // x_2 (consumed at step 0 write)
    float c_r = 0.f, hval = 0.f;
    __syncthreads();

    for (int t = 0; t < TT; t += 2) {
        STEP(0, t);
        STEP(1, t + 1);
    }
    // final h in h_s[0] (TT even)

    if (MODE == 2 && wv == 0) {
        float v = (ln < H) ? h_s[0][ln / 13][ln % 13] * wdr : 0.f;
#pragma unroll
        for (int off = 32; off > 0; off >>= 1) v += __shfl_down(v, off, 64);
        if (ln == 0) out[b] = v + b_dense[0];
    }
}

extern "C" void kernel_launch(void* const* d_in, const int* in_sizes, int n_in,
                              void* d_out, int out_size, void* d_ws, size_t ws_size,
                              hipStream_t stream) {
    const float* x     = (const float*)d_in[0];
    const float* wih1  = (const float*)d_in[1];
    const float* whh1  = (const float*)d_in[2];
    const float* bih1  = (const float*)d_in[3];
    const float* bhh1  = (const float*)d_in[4];
    const float* wih2  = (const float*)d_in[5];
    const float* whh2  = (const float*)d_in[6];
    const float* bih2  = (const float*)d_in[7];
    const float* bhh2  = (const float*)d_in[8];
    const float* wih3  = (const float*)d_in[9];
    const float* whh3  = (const float*)d_in[10];
    const float* bih3  = (const float*)d_in[11];
    const float* bhh3  = (const float*)d_in[12];
    const float* wd    = (const float*)d_in[13];
    const float* bd    = (const float*)d_in[14];
    float* outp = (float*)d_out;
    float* hbuf = (float*)d_ws;   // [B][T][H] fp32, in-place across layers

    lstm_kernel<0><<<BB, BLK, 0, stream>>>(x,    wih1, whh1, bih1, bhh1, hbuf, nullptr, nullptr, nullptr);
    lstm_kernel<1><<<BB, BLK, 0, stream>>>(hbuf, wih2, whh2, bih2, bhh2, hbuf, nullptr, nullptr, nullptr);
    lstm_kernel<2><<<BB, BLK, 0, stream>>>(hbuf, wih3, whh3, bih3, bhh3, nullptr, wd, bd, outp);
}

// Round 13
// 2256.154 us; speedup vs baseline: 1.1097x; 1.1097x over previous
//
#include <hip/hip_runtime.h>
#include <hip/hip_bf16.h>
#include <cstddef>

#define H    50
#define G4   200   // 4*H
#define TT   1024
#define BB   512
#define BLK  512   // 8 waves: waves 0..3 = h-waves (lane=(unit,qK)), 4..7 = x-waves

__device__ __forceinline__ float sigm(float x) { return 1.0f / (1.0f + __expf(-x)); }
__device__ __forceinline__ float tanh_fast(float x) { return 1.0f - 2.0f / (__expf(2.0f * x) + 1.0f); }

// lgkm-only barrier (global loads/stores stay in flight across the barrier)
#define BAR() do { asm volatile("s_waitcnt lgkmcnt(0)" ::: "memory"); \
                   __builtin_amdgcn_s_barrier(); } while (0)

// ---- 13 named scalar floats ----
#define D13(P) float P##0,P##1,P##2,P##3,P##4,P##5,P##6,P##7,P##8,P##9,P##10,P##11,P##12

// weight row slice: k = K0..K0+12, zero-padded past H (K0 = 13*q, q=3 has 2 pads)
#define WL13(P, WPTR, ROW, K0) do { const float* _w = (WPTR) + (size_t)(ROW) * H; const int _k = (K0); \
  P##0 =(_k+ 0<H)?_w[_k+ 0]:0.f; P##1 =(_k+ 1<H)?_w[_k+ 1]:0.f; P##2 =(_k+ 2<H)?_w[_k+ 2]:0.f; \
  P##3 =(_k+ 3<H)?_w[_k+ 3]:0.f; P##4 =(_k+ 4<H)?_w[_k+ 4]:0.f; P##5 =(_k+ 5<H)?_w[_k+ 5]:0.f; \
  P##6 =(_k+ 6<H)?_w[_k+ 6]:0.f; P##7 =(_k+ 7<H)?_w[_k+ 7]:0.f; P##8 =(_k+ 8<H)?_w[_k+ 8]:0.f; \
  P##9 =(_k+ 9<H)?_w[_k+ 9]:0.f; P##10=(_k+10<H)?_w[_k+10]:0.f; P##11=(_k+11<H)?_w[_k+11]:0.f; \
  P##12=(_k+12<H)?_w[_k+12]:0.f; } while (0)

// h slice from padded LDS (h_s has 52 entries; 50,51 are zero) — broadcast reads
#define HT13(P, HS, K0) float P##0=(HS)[(K0)+0], P##1=(HS)[(K0)+1], P##2 =(HS)[(K0)+2], \
  P##3=(HS)[(K0)+3], P##4=(HS)[(K0)+4],  P##5 =(HS)[(K0)+5],  P##6 =(HS)[(K0)+6], \
  P##7=(HS)[(K0)+7], P##8=(HS)[(K0)+8],  P##9 =(HS)[(K0)+9],  P##10=(HS)[(K0)+10], \
  P##11=(HS)[(K0)+11], P##12=(HS)[(K0)+12]

#define DOT13(W, X, A) do { \
  A=__fmaf_rn(W##0,X##0,A);  A=__fmaf_rn(W##1,X##1,A);  A=__fmaf_rn(W##2,X##2,A); \
  A=__fmaf_rn(W##3,X##3,A);  A=__fmaf_rn(W##4,X##4,A);  A=__fmaf_rn(W##5,X##5,A); \
  A=__fmaf_rn(W##6,X##6,A);  A=__fmaf_rn(W##7,X##7,A);  A=__fmaf_rn(W##8,X##8,A); \
  A=__fmaf_rn(W##9,X##9,A);  A=__fmaf_rn(W##10,X##10,A); A=__fmaf_rn(W##11,X##11,A); \
  A=__fmaf_rn(W##12,X##12,A); } while (0)

// x-wave global loads of x_step slice (BASE already includes k0x); pads re-read k0x
#define XL13(P, BASE) do { const size_t _b = (BASE); \
  P##0 = xrow[_b];                          P##1 =(k0x+ 1<H)?xrow[_b+ 1]:xrow[_b]; \
  P##2 =(k0x+ 2<H)?xrow[_b+ 2]:xrow[_b];    P##3 =(k0x+ 3<H)?xrow[_b+ 3]:xrow[_b]; \
  P##4 =(k0x+ 4<H)?xrow[_b+ 4]:xrow[_b];    P##5 =(k0x+ 5<H)?xrow[_b+ 5]:xrow[_b]; \
  P##6 =(k0x+ 6<H)?xrow[_b+ 6]:xrow[_b];    P##7 =(k0x+ 7<H)?xrow[_b+ 7]:xrow[_b]; \
  P##8 =(k0x+ 8<H)?xrow[_b+ 8]:xrow[_b];    P##9 =(k0x+ 9<H)?xrow[_b+ 9]:xrow[_b]; \
  P##10=(k0x+10<H)?xrow[_b+10]:xrow[_b];    P##11=(k0x+11<H)?xrow[_b+11]:xrow[_b]; \
  P##12=(k0x+12<H)?xrow[_b+12]:xrow[_b]; } while (0)

// x-wave: 4 partial dots from SRC regs -> xw_s[NB]
#define XCOMP(SRC, NB) do { float _p0=0.f,_p1=0.f,_p2=0.f,_p3=0.f; \
  DOT13(wA,SRC,_p0); DOT13(wB,SRC,_p1); DOT13(wC,SRC,_p2); DOT13(wD,SRC,_p3); \
  xw_s[NB][0][ux][qx]=_p0; xw_s[NB][1][ux][qx]=_p1; \
  xw_s[NB][2][ux][qx]=_p2; xw_s[NB][3][ux][qx]=_p3; } while (0)

// One time step. CUR compile-time 0/1. XSRC holds x_{T+1}; XDST receives x_{T+2}.
#define STEP(CUR, T, XSRC, XDST) do { \
  if (hw) { \
    HT13(ht, h_s[CUR], k0h); \
    float a0=0.f, a1=0.f, a2=0.f, a3=0.f; \
    DOT13(wA, ht, a0); DOT13(wB, ht, a1); DOT13(wC, ht, a2); DOT13(wD, ht, a3); \
    if (MODE != 0) { \
      a0 += xw_s[CUR][0][uh][qh]; a1 += xw_s[CUR][1][uh][qh]; \
      a2 += xw_s[CUR][2][uh][qh]; a3 += xw_s[CUR][3][uh][qh]; \
    } \
    a0 += __shfl_xor(a0, 1); a0 += __shfl_xor(a0, 2); \
    a1 += __shfl_xor(a1, 1); a1 += __shfl_xor(a1, 2); \
    a2 += __shfl_xor(a2, 1); a2 += __shfl_xor(a2, 2); \
    a3 += __shfl_xor(a3, 1); a3 += __shfl_xor(a3, 2); \
    if (MODE == 0) { float _xt = x_s[T]; \
      a0 = __fmaf_rn(wi0,_xt,a0); a1 = __fmaf_rn(wi1,_xt,a1); \
      a2 = __fmaf_rn(wi2,_xt,a2); a3 = __fmaf_rn(wi3,_xt,a3); } \
    float iv = sigm(a0 + bb0), fv = sigm(a1 + bb1); \
    float gv = tanh_fast(a2 + bb2), ov = sigm(a3 + bb3); \
    c_r  = __fmaf_rn(fv, c_r, iv * gv); \
    hval = ov * tanh_fast(c_r); \
    if (hvalid) { \
      h_s[(CUR)^1][uh] = hval; \
      if (MODE != 2) hout[hob + (size_t)(T) * H + uh] = hval; \
    } \
  } else if (MODE != 0) { \
    if ((T) + 2 < TT) { XL13(XDST, (size_t)((T)+2) * H + k0x); } \
    if ((T) + 1 < TT) { XCOMP(XSRC, (CUR)^1); } \
  } \
  BAR(); \
} while (0)

// MODE 0: first layer (scalar x); MODE 1: middle; MODE 2: last + dense head
template <int MODE>
__global__ __launch_bounds__(BLK)
void lstm_kernel(
    const float* __restrict__ xin,
    const float* __restrict__ w_ih,    // [G4][H] (MODE0: [G4][1])
    const float* __restrict__ w_hh,    // [G4][H]
    const float* __restrict__ b_ih,    // [G4]
    const float* __restrict__ b_hh,    // [G4]
    float* __restrict__ hout,          // [B][T][H] (MODE 0,1)
    const float* __restrict__ w_dense, // [H]   (MODE 2)
    const float* __restrict__ b_dense, // [1]   (MODE 2)
    float* __restrict__ out)           // [B]   (MODE 2)
{
    const int b   = blockIdx.x;
    const int tid = threadIdx.x;
    const int wv  = tid >> 6;
    const int ln  = tid & 63;
    const bool hw = (wv < 4);                    // h-wave role

    // h-wave mapping: unit uh = wv*16 + ln/4 (valid < 50), K-quarter qh = ln&3
    const int uh  = (wv & 3) * 16 + (ln >> 2);
    const int qh  = ln & 3;
    const int k0h = 13 * qh;
    const int uch = (uh < H) ? uh : (H - 1);
    const bool hvalid = hw && (uh < H) && (qh == 0);

    // x-wave mapping (same shape)
    const int ux  = uh, qx = qh, k0x = k0h, ucx = uch;

    __shared__ float h_s[2][52];                 // padded: [50],[51] stay 0
    __shared__ float xw_s[2][4][64][4];          // [buf][gate][unit][q] partial x-dots
    __shared__ float x_s[MODE == 0 ? TT : 1];    // MODE0: whole scalar input row

    // Occupancy shaper: 52 KB dummy LDS -> total LDS ~58-62 KB -> max 2
    // blocks/CU -> RA/scheduler target occupancy 4 waves/EU -> VGPR budget 128.
    // (Rounds 1-12: at the default 8-waves/EU target the budget is 64 VGPR and
    // the allocator demotes the 52 weight floats into per-step L1/L2 reloads —
    // ~212 KB/step/CU of L2 traffic = the measured 100% VALUBusy plateau.)
    __shared__ float wforce[13312];
    wforce[tid] = 0.f;
    { float _kv = wforce[tid ^ 1];
      asm volatile("" :: "v"(_kv)); }           // keep allocation live

    // ---- weights: 4 gate rows x 13-slice = 52 named scalars (resident scale) ----
    D13(wA); D13(wB); D13(wC); D13(wD);
    D13(xa); D13(xb);                            // x-wave double-buffered x slices
    float wi0 = 0.f, wi1 = 0.f, wi2 = 0.f, wi3 = 0.f;  // MODE0 scalar x-weights
    float bb0 = 0.f, bb1 = 0.f, bb2 = 0.f, bb3 = 0.f;

    const float* __restrict__ xrow = xin + (size_t)b * TT * (MODE == 0 ? 1 : H);
    const size_t hob = (size_t)b * TT * H;

    if (hw) {
        WL13(wA, w_hh, 0 * H + uch, k0h);
        WL13(wB, w_hh, 1 * H + uch, k0h);
        WL13(wC, w_hh, 2 * H + uch, k0h);
        WL13(wD, w_hh, 3 * H + uch, k0h);
        bb0 = b_ih[0 * H + uch] + b_hh[0 * H + uch];
        bb1 = b_ih[1 * H + uch] + b_hh[1 * H + uch];
        bb2 = b_ih[2 * H + uch] + b_hh[2 * H + uch];
        bb3 = b_ih[3 * H + uch] + b_hh[3 * H + uch];
        if (MODE == 0) {
            wi0 = w_ih[0 * H + uch]; wi1 = w_ih[1 * H + uch];
            wi2 = w_ih[2 * H + uch]; wi3 = w_ih[3 * H + uch];
        }
    } else if (MODE != 0) {
        WL13(wA, w_ih, 0 * H + ucx, k0x);
        WL13(wB, w_ih, 1 * H + ucx, k0x);
        WL13(wC, w_ih, 2 * H + ucx, k0x);
        WL13(wD, w_ih, 3 * H + ucx, k0x);
    }
    float wdr = 0.f;
    if (MODE == 2 && wv == 0 && ln < H) wdr = w_dense[ln];

    // ---- init LDS ----
    if (tid < 104) (&h_s[0][0])[tid] = 0.f;
    if (MODE == 0) {
        for (int i = tid; i < TT; i += BLK) x_s[i] = xrow[i];
    } else if (!hw) {
        XL13(xb, (size_t)0 * H + k0x);   // x_0 (scratch)
        XCOMP(xb, 0);                    // xw partials for t=0
        XL13(xa, (size_t)1 * H + k0x);   // x_1 for STEP(0, t=0)
    }
    float c_r = 0.f, hval = 0.f;
    __syncthreads();                      // one-time full barrier (init visibility)

    for (int t = 0; t < TT; t += 2) {
        STEP(0, t,     xa, xb);
        STEP(1, t + 1, xb, xa);
    }
    // final h is in h_s[0] (TT even)

    if (MODE == 2 && wv == 0) {
        float v = (ln < H) ? h_s[0][ln] * wdr : 0.f;
#pragma unroll
        for (int off = 32; off > 0; off >>= 1) v += __shfl_down(v, off, 64);
        if (ln == 0) out[b] = v + b_dense[0];
    }
}

extern "C" void kernel_launch(void* const* d_in, const int* in_sizes, int n_in,
                              void* d_out, int out_size, void* d_ws, size_t ws_size,
                              hipStream_t stream) {
    const float* x     = (const float*)d_in[0];
    const float* wih1  = (const float*)d_in[1];
    const float* whh1  = (const float*)d_in[2];
    const float* bih1  = (const float*)d_in[3];
    const float* bhh1  = (const float*)d_in[4];
    const float* wih2  = (const float*)d_in[5];
    const float* whh2  = (const float*)d_in[6];
    const float* bih2  = (const float*)d_in[7];
    const float* bhh2  = (const float*)d_in[8];
    const float* wih3  = (const float*)d_in[9];
    const float* whh3  = (const float*)d_in[10];
    const float* bih3  = (const float*)d_in[11];
    const float* bhh3  = (const float*)d_in[12];
    const float* wd    = (const float*)d_in[13];
    const float* bd    = (const float*)d_in[14];
    float* outp = (float*)d_out;
    float* hbuf = (float*)d_ws;   // [B][T][H] fp32, in-place across layers

    lstm_kernel<0><<<BB, BLK, 0, stream>>>(x,    wih1, whh1, bih1, bhh1, hbuf, nullptr, nullptr, nullptr);
    lstm_kernel<1><<<BB, BLK, 0, stream>>>(hbuf, wih2, whh2, bih2, bhh2, hbuf, nullptr, nullptr, nullptr);
    lstm_kernel<2><<<BB, BLK, 0, stream>>>(hbuf, wih3, whh3, bih3, bhh3, nullptr, wd, bd, outp);
}